// Round 2
// baseline (107.670 us; speedup 1.0000x reference)
//
#include <hip/hip_runtime.h>
#include <hip/hip_bf16.h>

#define HIDDEN 512
#define SEQ 256

// One thread: one h row, 4 consecutive 16-chunks (256B of x in registers).
// W rows streamed from global (L2/L1-resident, 512KB total, reused by all b).
// y[t,o] = sum_g W[h,o,g] * x[t,g]
__device__ __forceinline__ float dot16(const float4& x0, const float4& x1,
                                       const float4& x2, const float4& x3,
                                       const float4& w0, const float4& w1,
                                       const float4& w2, const float4& w3) {
  float a;
  a = x0.x * w0.x;
  a = fmaf(x0.y, w0.y, a);
  a = fmaf(x0.z, w0.z, a);
  a = fmaf(x0.w, w0.w, a);
  a = fmaf(x1.x, w1.x, a);
  a = fmaf(x1.y, w1.y, a);
  a = fmaf(x1.z, w1.z, a);
  a = fmaf(x1.w, w1.w, a);
  a = fmaf(x2.x, w2.x, a);
  a = fmaf(x2.y, w2.y, a);
  a = fmaf(x2.z, w2.z, a);
  a = fmaf(x2.w, w2.w, a);
  a = fmaf(x3.x, w3.x, a);
  a = fmaf(x3.y, w3.y, a);
  a = fmaf(x3.z, w3.z, a);
  a = fmaf(x3.w, w3.w, a);
  return a;
}

__global__ __launch_bounds__(256) void LocalMixer_47579647705675_kernel(
    const float* __restrict__ x, const float* __restrict__ W,
    float* __restrict__ y) {
  const int blk = blockIdx.x;
  const int b  = blk >> 3;         // 8 h-tiles (of 64 h) per b
  const int ht = blk & 7;
  const int hl = threadIdx.x >> 2; // 64 h per block
  const int tq = threadIdx.x & 3;  // 4 chunk-quads per h
  const int h  = (ht << 6) + hl;

  const size_t row = ((size_t)b * HIDDEN + h) * SEQ;

  // Load this thread's 4 chunks: 64 contiguous floats = 16 float4.
  const float4* xp = reinterpret_cast<const float4*>(x + row) + tq * 16;
  float4 xr[16];
#pragma unroll
  for (int j = 0; j < 16; ++j) xr[j] = xp[j];

  const float4* Wp = reinterpret_cast<const float4*>(W + (size_t)h * 256);
  float4* yp = reinterpret_cast<float4*>(y + row) + tq * 16;

#pragma unroll
  for (int oq = 0; oq < 4; ++oq) {
    float acc[4][4];  // [chunk k][oi]
#pragma unroll
    for (int oi = 0; oi < 4; ++oi) {
      const int o = oq * 4 + oi;
      const float4 w0 = Wp[4 * o + 0];
      const float4 w1 = Wp[4 * o + 1];
      const float4 w2 = Wp[4 * o + 2];
      const float4 w3 = Wp[4 * o + 3];
#pragma unroll
      for (int k = 0; k < 4; ++k) {
        acc[k][oi] = dot16(xr[4 * k + 0], xr[4 * k + 1], xr[4 * k + 2],
                           xr[4 * k + 3], w0, w1, w2, w3);
      }
    }
#pragma unroll
    for (int k = 0; k < 4; ++k) {
      yp[k * 4 + oq] =
          make_float4(acc[k][0], acc[k][1], acc[k][2], acc[k][3]);
    }
  }
}

extern "C" void kernel_launch(void* const* d_in, const int* in_sizes, int n_in,
                              void* d_out, int out_size, void* d_ws, size_t ws_size,
                              hipStream_t stream) {
  const float* x = (const float*)d_in[0];
  const float* W = (const float*)d_in[1];
  float* y = (float*)d_out;

  const int B = in_sizes[0] / (HIDDEN * SEQ);  // 256
  const int grid = B * (HIDDEN / 64);          // 2048 blocks
  LocalMixer_47579647705675_kernel<<<grid, 256, 0, stream>>>(x, W, y);
}

// Round 3
// 59.770 us; speedup vs baseline: 1.8014x; 1.8014x over previous
//
#include <hip/hip_runtime.h>
#include <hip/hip_bf16.h>

#define HIDDEN 512
#define SEQ 256

// One wave = one h, 4 batches, 16 chunks (lane = bl*16 + t).
// W row (1 KB) is wave-uniform -> scalar/L1 loads, no LDS.
// Each lane: 16 contiguous x floats in regs, 16 outputs, contiguous stores.
__device__ __forceinline__ float dot16(const float4& x0, const float4& x1,
                                       const float4& x2, const float4& x3,
                                       const float4& w0, const float4& w1,
                                       const float4& w2, const float4& w3) {
  float a;
  a = x0.x * w0.x;
  a = fmaf(x0.y, w0.y, a);
  a = fmaf(x0.z, w0.z, a);
  a = fmaf(x0.w, w0.w, a);
  a = fmaf(x1.x, w1.x, a);
  a = fmaf(x1.y, w1.y, a);
  a = fmaf(x1.z, w1.z, a);
  a = fmaf(x1.w, w1.w, a);
  a = fmaf(x2.x, w2.x, a);
  a = fmaf(x2.y, w2.y, a);
  a = fmaf(x2.z, w2.z, a);
  a = fmaf(x2.w, w2.w, a);
  a = fmaf(x3.x, w3.x, a);
  a = fmaf(x3.y, w3.y, a);
  a = fmaf(x3.z, w3.z, a);
  a = fmaf(x3.w, w3.w, a);
  return a;
}

__global__ __launch_bounds__(256) void LocalMixer_47579647705675_kernel(
    const float* __restrict__ x, const float* __restrict__ W,
    float* __restrict__ y) {
  const int tid  = threadIdx.x;
  const int wave = tid >> 6;
  const int lane = tid & 63;
  const int bl   = lane >> 4;  // batch within wave (4)
  const int t    = lane & 15;  // chunk within row (16)

  const int blk    = blockIdx.x;
  const int b_tile = blk >> 7;   // 64 tiles of 4 b
  const int h_tile = blk & 127;  // 128 tiles of 4 h
  const int b = b_tile * 4 + bl;
  int h = h_tile * 4 + wave;
  h = __builtin_amdgcn_readfirstlane(h);  // force SGPR base for W

  const size_t row = ((size_t)b * HIDDEN + h) * SEQ + (size_t)t * 16;

  // Load this lane's chunk: 16 contiguous floats.
  const float4* xp = reinterpret_cast<const float4*>(x + row);
  float4 xr0 = xp[0], xr1 = xp[1], xr2 = xp[2], xr3 = xp[3];

  const float4* Wp = reinterpret_cast<const float4*>(W + (size_t)h * 256);
  float4* yp = reinterpret_cast<float4*>(y + row);

  float4 out[4];
#pragma unroll
  for (int oq = 0; oq < 4; ++oq) {
    float acc[4];
#pragma unroll
    for (int oi = 0; oi < 4; ++oi) {
      const int o = oq * 4 + oi;
      const float4 w0 = Wp[4 * o + 0];
      const float4 w1 = Wp[4 * o + 1];
      const float4 w2 = Wp[4 * o + 2];
      const float4 w3 = Wp[4 * o + 3];
      acc[oi] = dot16(xr0, xr1, xr2, xr3, w0, w1, w2, w3);
    }
    out[oq] = make_float4(acc[0], acc[1], acc[2], acc[3]);
  }

  // Back-to-back contiguous stores (R1-proven merge pattern).
#pragma unroll
  for (int oq = 0; oq < 4; ++oq) yp[oq] = out[oq];
}

extern "C" void kernel_launch(void* const* d_in, const int* in_sizes, int n_in,
                              void* d_out, int out_size, void* d_ws, size_t ws_size,
                              hipStream_t stream) {
  const float* x = (const float*)d_in[0];
  const float* W = (const float*)d_in[1];
  float* y = (float*)d_out;

  const int B = in_sizes[0] / (HIDDEN * SEQ);    // 256
  const int grid = (B / 4) * (HIDDEN / 4);       // 8192 blocks
  LocalMixer_47579647705675_kernel<<<grid, 256, 0, stream>>>(x, W, y);
}